// Round 1
// baseline (636.233 us; speedup 1.0000x reference)
//
#include <hip/hip_runtime.h>
#include <hip/hip_bf16.h>

typedef __bf16 bf16;
typedef __attribute__((ext_vector_type(8))) __bf16 bf16x8;
typedef __attribute__((ext_vector_type(4))) float f32x4;

#define E_EDGES 262144
#define MT 128   // rows per block

// Pre-pass: transpose + fp32->bf16 convert weights into workspace.
// W1 fp32 [384][512] -> W1t bf16 [512][384];  W2 fp32 [512][128] -> W2t bf16 [128][512]
__global__ void transpose_w(const float* __restrict__ W1, const float* __restrict__ W2,
                            bf16* __restrict__ W1t, bf16* __restrict__ W2t)
{
  int tid = blockIdx.x * 256 + threadIdx.x;
  if (tid < 512 * 384) {
    int n = tid / 384;
    int k = tid - n * 384;
    W1t[tid] = (bf16)W1[k * 512 + n];
  }
  if (tid < 128 * 512) {
    int n = tid >> 9;
    int k = tid & 511;
    W2t[tid] = (bf16)W2[k * 128 + n];
  }
}

__device__ __forceinline__ bf16x8 cvt8v(f32x4 a, f32x4 b) {
  bf16x8 r;
  r[0] = (bf16)a[0]; r[1] = (bf16)a[1]; r[2] = (bf16)a[2]; r[3] = (bf16)a[3];
  r[4] = (bf16)b[0]; r[5] = (bf16)b[1]; r[6] = (bf16)b[2]; r[7] = (bf16)b[3];
  return r;
}

// async global->LDS, 16B per lane; LDS dest must be wave-uniform (HW writes base + lane*16)
__device__ __forceinline__ void glds16(const void* g, void* l) {
  __builtin_amdgcn_global_load_lds(
      (const __attribute__((address_space(1))) void*)g,
      (__attribute__((address_space(3))) void*)l,
      16, 0, 0);
}

// Fused: h = silu(concat(x_i,x_j,ea) @ W1 + b1); y = LN(h @ W2 + b2)*g + b + ea
__global__ __launch_bounds__(512, 4)
void fused_edge_mlp(const float* __restrict__ x_i,
                    const float* __restrict__ x_j,
                    const float* __restrict__ ea,
                    const bf16* __restrict__ W1t,
                    const float* __restrict__ b1,
                    const bf16* __restrict__ W2t,
                    const float* __restrict__ b2,
                    const float* __restrict__ gmm,
                    const float* __restrict__ bta,
                    float* __restrict__ out)
{
  // A tiles for GEMM1; aliased as W2 tiles during GEMM2. XOR-swizzled layout.
  __shared__ bf16 As[2][128 * 32];    // 2 x 8KB
  __shared__ bf16 Bs[2][128 * 32];    // 2 x 8KB (W1 tiles)
  __shared__ bf16 H1s[128 * 136];     // 34.8KB, +8 pad
  // total 66KB -> 2 blocks/CU

  const int t    = threadIdx.x;
  const int w    = t >> 6;             // wave 0..7
  const int lane = t & 63;
  const int l15  = lane & 15;
  const int q    = lane >> 4;          // quad 0..3
  const int srow = t >> 2;             // staging row 0..127 (4 threads/row)
  const int sc   = t & 3;              // staging 16B-block col 0..3
  const int scf  = sc << 3;            // float col offset (0,8,16,24)
  const int swz  = (sc ^ ((srow >> 1) & 3)) << 3;  // swizzled bf16 col offset (write/src side)
  const int rsw  = (l15 >> 1) & 3;     // read-side swizzle term ((row>>1)&3 for row=16k+l15)
  const int wm   = w >> 2;             // GEMM1 row half (64 rows)
  const int wn   = w & 3;              // GEMM1 col quarter (32 cols)
  const long m0  = (long)blockIdx.x * MT;
  const int wb   = (t & ~63) << 3;     // wave-uniform LDS elem base for glds16 (1KB/wave)

  const f32x4 fzero = {0.f, 0.f, 0.f, 0.f};

  // preload b1 for all 4 nc chunks (this thread's 2 columns per chunk)
  float b1r[8];
  #pragma unroll
  for (int j = 0; j < 8; ++j)
    b1r[j] = b1[(j >> 1) * 128 + 32 * wn + 16 * (j & 1) + l15];

  f32x4 acc2[8];                       // C2 [16 x 128] per wave (rows 16w..16w+15)
  #pragma unroll
  for (int i = 0; i < 8; ++i) acc2[i] = fzero;

  // ---- prologue: stage (nc=0, kk=0) into buffer 0 ----
  {
    const float* pA = x_i + (m0 + srow) * 128 + scf;
    f32x4 a0 = *(const f32x4*)pA;
    f32x4 a1 = *(const f32x4*)(pA + 4);
    glds16(W1t + (long)srow * 384 + swz, &Bs[0][wb]);
    *(bf16x8*)&As[0][srow * 32 + swz] = cvt8v(a0, a1);
    __syncthreads();
  }

  int p = 0;
  for (int nc = 0; nc < 4; ++nc) {
    f32x4 acc1[8];                     // C1 [64 x 32] per wave
    #pragma unroll
    for (int i = 0; i < 8; ++i) acc1[i] = fzero;

    // ---- GEMM1: 12 K-steps of 32; single barrier per step, depth-1 prefetch ----
    for (int kk = 0; kk < 12; ++kk) {
      f32x4 a0, a1;
      if (kk < 11) {
        // stage next K-step into buffers p^1
        const int k1 = kk + 1;
        const float* sA = (k1 < 4) ? x_i : (k1 < 8) ? x_j : ea;
        const float* pA = sA + (m0 + srow) * 128 + ((k1 & 3) << 5) + scf;
        a0 = *(const f32x4*)pA;
        a1 = *(const f32x4*)(pA + 4);
        glds16(W1t + (long)(nc * 128 + srow) * 384 + (k1 << 5) + swz, &Bs[p ^ 1][wb]);
      } else {
        // cross-phase prefetch: W2 chunk s4=0 into the A-buffer space
        glds16(W2t + (long)srow * 512 + (nc << 7) + swz, &As[p ^ 1][wb]);
      }

      // compute on buffers p
      bf16x8 af[4], bfr[2];
      #pragma unroll
      for (int mi = 0; mi < 4; ++mi)
        af[mi] = *(const bf16x8*)&As[p][(64 * wm + 16 * mi + l15) * 32 + ((q ^ rsw) << 3)];
      #pragma unroll
      for (int ni = 0; ni < 2; ++ni)
        bfr[ni] = *(const bf16x8*)&Bs[p][(32 * wn + 16 * ni + l15) * 32 + ((q ^ rsw) << 3)];
      #pragma unroll
      for (int mi = 0; mi < 4; ++mi)
        #pragma unroll
        for (int ni = 0; ni < 2; ++ni)
          acc1[mi * 2 + ni] = __builtin_amdgcn_mfma_f32_16x16x32_bf16(
              af[mi], bfr[ni], acc1[mi * 2 + ni], 0, 0, 0);

      if (kk < 11) {
        // finish A staging for next step (swizzled ds_write)
        *(bf16x8*)&As[p ^ 1][srow * 32 + swz] = cvt8v(a0, a1);
      } else {
        // epilogue: bias + SiLU -> H1s (C/D layout -> row-major LDS)
        #pragma unroll
        for (int mi = 0; mi < 4; ++mi)
          #pragma unroll
          for (int ni = 0; ni < 2; ++ni)
            #pragma unroll
            for (int i = 0; i < 4; ++i) {
              float s = acc1[mi * 2 + ni][i] + b1r[(nc << 1) + ni];
              float h = s / (1.f + __expf(-s));
              H1s[(64 * wm + 16 * mi + 4 * q + i) * 136 + 32 * wn + 16 * ni + l15] = (bf16)h;
            }
      }
      __syncthreads();
      p ^= 1;
    }

    // ---- GEMM2 partial: C2 += H1chunk[128,128] @ W2chunk^T; W2 tiles alias As ----
    for (int s4 = 0; s4 < 4; ++s4) {
      f32x4 a0, a1;
      bool stA = false;
      if (s4 < 3) {
        glds16(W2t + (long)srow * 512 + (nc << 7) + ((s4 + 1) << 5) + swz, &As[p ^ 1][wb]);
      } else if (nc < 3) {
        // cross-phase prefetch: next nc's K-step 0 (A and B)
        glds16(W1t + (long)((nc + 1) * 128 + srow) * 384 + swz, &Bs[p ^ 1][wb]);
        const float* pA = x_i + (m0 + srow) * 128 + scf;
        a0 = *(const f32x4*)pA;
        a1 = *(const f32x4*)(pA + 4);
        stA = true;
      }

      bf16x8 a2 = *(const bf16x8*)&H1s[(16 * w + l15) * 136 + (s4 << 5) + (q << 3)];
      #pragma unroll
      for (int ni = 0; ni < 8; ++ni) {
        bf16x8 b2f = *(const bf16x8*)&As[p][(16 * ni + l15) * 32 + ((q ^ rsw) << 3)];
        acc2[ni] = __builtin_amdgcn_mfma_f32_16x16x32_bf16(a2, b2f, acc2[ni], 0, 0, 0);
      }

      if (stA)
        *(bf16x8*)&As[p ^ 1][srow * 32 + swz] = cvt8v(a0, a1);
      __syncthreads();
      p ^= 1;
    }
  }

  // ---- LN + gamma/beta + residual; wave w owns rows [16w,16w+16) ----
  float b2v[8], gv[8], bv[8];
  #pragma unroll
  for (int ni = 0; ni < 8; ++ni) {
    int n = 16 * ni + l15;
    b2v[ni] = b2[n];
    gv[ni]  = gmm[n];
    bv[ni]  = bta[n];
  }
  #pragma unroll
  for (int ni = 0; ni < 8; ++ni)
    #pragma unroll
    for (int i = 0; i < 4; ++i)
      acc2[ni][i] += b2v[ni];

  #pragma unroll
  for (int i = 0; i < 4; ++i) {
    float s = 0.f, s2 = 0.f;
    #pragma unroll
    for (int ni = 0; ni < 8; ++ni) {
      float v = acc2[ni][i];
      s += v;
      s2 += v * v;
    }
    // reduce across the 16 lanes of this quad (row r=4q+i lives in one quad)
    #pragma unroll
    for (int off = 1; off <= 8; off <<= 1) {
      s  += __shfl_xor(s,  off, 64);
      s2 += __shfl_xor(s2, off, 64);
    }
    float mu   = s * (1.f / 128.f);
    float var  = fmaxf(s2 * (1.f / 128.f) - mu * mu, 0.f);
    float rstd = rsqrtf(var + 1e-5f);
    long  mg   = m0 + 16 * w + 4 * q + i;
    #pragma unroll
    for (int ni = 0; ni < 8; ++ni) {
      int n = 16 * ni + l15;
      float o = (acc2[ni][i] - mu) * rstd * gv[ni] + bv[ni] + ea[mg * 128 + n];
      out[mg * 128 + n] = o;
    }
  }
}

extern "C" void kernel_launch(void* const* d_in, const int* in_sizes, int n_in,
                              void* d_out, int out_size, void* d_ws, size_t ws_size,
                              hipStream_t stream)
{
  const float* x_i = (const float*)d_in[0];
  const float* x_j = (const float*)d_in[1];
  const float* ea  = (const float*)d_in[2];
  const float* W1  = (const float*)d_in[3];
  const float* b1  = (const float*)d_in[4];
  const float* W2  = (const float*)d_in[5];
  const float* b2  = (const float*)d_in[6];
  const float* gm  = (const float*)d_in[7];
  const float* bt  = (const float*)d_in[8];
  float* outp = (float*)d_out;
  bf16* W1t = (bf16*)d_ws;           // 512*384 bf16
  bf16* W2t = W1t + 512 * 384;       // 128*512 bf16

  hipLaunchKernelGGL(transpose_w, dim3(768), dim3(256), 0, stream, W1, W2, W1t, W2t);
  hipLaunchKernelGGL(fused_edge_mlp, dim3(E_EDGES / MT), dim3(512), 0, stream,
                     x_i, x_j, ea, W1t, b1, W2t, b2, gm, bt, outp);
}